// Round 2
// 30271.591 us; speedup vs baseline: 1.0794x; 1.0794x over previous
//
#include <hip/hip_runtime.h>
#include <hip/hip_bf16.h>

typedef __hip_bfloat16 bf16;
typedef _Float16 f16;
typedef _Float16 f16x8 __attribute__((ext_vector_type(8)));
typedef float f32x4 __attribute__((ext_vector_type(4)));
typedef unsigned long long u64;
typedef unsigned short ushort_t;

__device__ __forceinline__ float b2f(bf16 x){ return __bfloat162float(x); }
__device__ __forceinline__ float sigf(float x){ return 1.f/(1.f+expf(-x)); }
__device__ __forceinline__ float splus(float x){ return fmaxf(x,0.f)+log1pf(expf(-fabsf(x))); }
__device__ __forceinline__ float ldf(const void* p, int i, int isf32){
  return isf32 ? ((const float*)p)[i] : __bfloat162float(((const bf16*)p)[i]);
}
// agent-scope coherent ops: serviced at the device coherence point (bypass per-XCD L2).
// Prior rounds passing prove these are cross-XCD coherent with NO fences.
__device__ __forceinline__ void ast64(u64* p, u64 v){ __hip_atomic_store(p, v, __ATOMIC_RELAXED, __HIP_MEMORY_SCOPE_AGENT); }
__device__ __forceinline__ u64 ald64(u64* p){ return __hip_atomic_load(p, __ATOMIC_RELAXED, __HIP_MEMORY_SCOPE_AGENT); }
__device__ __forceinline__ void ast32(unsigned* p, unsigned v){ __hip_atomic_store(p, v, __ATOMIC_RELAXED, __HIP_MEMORY_SCOPE_AGENT); }
__device__ __forceinline__ unsigned ald32(unsigned* p){ return __hip_atomic_load(p, __ATOMIC_RELAXED, __HIP_MEMORY_SCOPE_AGENT); }

union U4H8 { uint4 u; f16x8 h; };
union U64H4 { u64 u; f16 h[4]; };
union U32H2 { unsigned u; f16 h[2]; };
union H16 { f16 h; ushort_t s; };

// ---------------- dtype detect ----------------
__global__ void k_detect(const void* __restrict__ emb, int* __restrict__ flag){
  __shared__ float mx[256];
  int tid=threadIdx.x;
  float v = fabsf(__bfloat162float(((const bf16*)emb)[tid]));
  mx[tid]=v; __syncthreads();
  for(int s=128;s>0;s>>=1){ if(tid<s) mx[tid]=fmaxf(mx[tid],mx[tid+s]); __syncthreads(); }
  if(tid==0){ flag[0] = (mx[0]>1000.f) ? 1 : 0; flag[1] = 0; }
}

// ---------------- setup ----------------
// embW[row][v] = b0[row] + sum_k emb[v][k]*Wi0[row][k]
__global__ void k_embW(const void* __restrict__ emb, const void* __restrict__ Wi0,
                       const void* __restrict__ b0,
                       const int* __restrict__ flags, float* __restrict__ embW){
  int f=flags[0];
  int row = blockIdx.x;
  __shared__ float w[512];
  for(int k=threadIdx.x;k<512;k+=256) w[k]=ldf(Wi0,row*576+k,f);
  __syncthreads();
  int v = threadIdx.x;
  float acc=ldf(b0,row,f);
  #pragma unroll 4
  for(int k=0;k<512;k++) acc += ldf(emb,v*512+k,f)*w[k];
  embW[row*256+v]=acc;
}

// prepack phase-A weights into MFMA A-fragment order (f16)
__global__ void k_wpkA(const void* __restrict__ Wh0, const void* __restrict__ Wi0,
                       const int* __restrict__ flags, ushort_t* __restrict__ PA){
  int f=flags[0];
  int idx=blockIdx.x*256+threadIdx.x;
  if(idx>=1310720) return;
  int j=idx&7, lcl=(idx>>3)&63, fi=idx>>9;
  int c=fi%5, tq=fi/5, v=tq&7, q=tq>>3;
  int kh=v>>1, rt=v&1, m=lcl&15, quad=lcl>>4;
  int chunk=c*4+kh;
  int ri=rt*16+m, g=ri>>3, u=ri&7, row=(g<<9)+(q<<3)+u;
  int k=chunk*32+quad*8+j;
  float val=0.f;
  if(chunk<18) val = (k<512)? ldf(Wh0,row*512+k,f) : ldf(Wi0,row*576+k,f);
  H16 hh; hh.h=(f16)val; PA[idx]=hh.s;
}
__global__ void k_wpkB(const void* __restrict__ Wi1, const void* __restrict__ Wh1,
                       const int* __restrict__ flags, ushort_t* __restrict__ PB){
  int f=flags[0];
  int idx=blockIdx.x*256+threadIdx.x;
  if(idx>=2097152) return;
  int j=idx&7, lcl=(idx>>3)&63, c=(idx>>9)&7, v=(idx>>12)&7, q=idx>>15;
  int kh=v>>1, rt=v&1, m=lcl&15, quad=lcl>>4;
  int chunk=c*4+kh;
  int ri=rt*16+m, g=ri>>3, u=ri&7, row=(g<<9)+(q<<3)+u;
  int k=chunk*32+quad*8+j;
  float val = (k<512)? ldf(Wi1,row*512+k,f) : ldf(Wh1,row*512+k-512,f);
  H16 hh; hh.h=(f16)val; PB[idx]=hh.s;
}

// W_ifT layout is [512][136]; column 135 is padding.  We repurpose the 512
// padding dwords as the sync-flag array for k_dnc3: flag of block q lives at
// dword q*1088+135 (its own 4352B-separated line).  Must be zeroed here.
__global__ void k_wifT(const void* __restrict__ W_if, const void* __restrict__ b_if,
                       const int* __restrict__ flags,
                       float* __restrict__ W_ifT, float* __restrict__ b_ifF){
  int f=flags[0];
  int idx=blockIdx.x*256+threadIdx.x;
  if(idx<135*512){ int v=idx/512, k=idx-v*512; W_ifT[k*136+v]=ldf(W_if,idx,f); }
  if(idx<512) W_ifT[idx*136+135]=0.f;     // zero the flag column
  if(idx<135) b_ifF[idx]=ldf(b_if,idx,f);
}

__global__ void k_wc(const void* __restrict__ W_fc, const void* __restrict__ W_out,
                     const void* __restrict__ b_out, const void* __restrict__ b_fc,
                     const int* __restrict__ flags,
                     float* __restrict__ Wc, float* __restrict__ bc){
  int f=flags[0];
  int idx=blockIdx.x*256+threadIdx.x;
  int v=idx/576, j=idx-v*576;
  float acc=0.f;
  #pragma unroll 4
  for(int d=0;d<512;d++) acc += ldf(W_fc,v*512+d,f)*ldf(W_out,d*576+j,f);
  Wc[idx]=acc;
  if(j==0){
    float a=ldf(b_fc,v,f);
    for(int d=0;d<512;d++) a += ldf(W_fc,v*512+d,f)*ldf(b_out,d,f);
    bc[v]=a;
  }
}

// ---------------- cooperative recurrence, flag-pipelined ----------------
// Sync protocol: one monotone u32 flag per block (in W_ifT's pad column).
//   init       -> 1
//   alpha(t)   -> 3t+2   (h0(t) slices in GH0[p] published)
//   beta(t)    -> 3t+3   (h1(t) slices in GH1[p] published)
//   gamma(t)   -> 3t+4   (lr(t) in GLR[p] published)
// PUBLISH = __syncthreads (drains vmcnt(0) for every wave -> all agent-scope
// data stores are at the coherence point) then tid0 stores the flag value.
// WAIT(v) = wave 0 polls all 64 flags (lane l watches block l) until >= v.
// Producers never stop at a barrier; consumers wait only when they must, and
// each wait is preceded by independent MFMA/staging work:
//   gamma(t-1) wait is covered by A(t)'s 16 h0-chunks,
//   alpha(t)   wait is covered by B(t)'s 16 h1prev-chunks.
// Buffer-overwrite safety under skew was verified for GH0/GH1/GLR: every
// overwrite at step t is ordered (via the flag chain) after all readers of
// the previous content.
// WATCHDOG: poll loops are bounded (~50M iters, seconds). A true protocol
// deadlock then surfaces as passed:false instead of a container timeout.
__global__ void __launch_bounds__(512) k_dnc3(
    const int* __restrict__ tokens, const void* __restrict__ b1, const int* __restrict__ flags,
    const float* __restrict__ embW, const ushort_t* __restrict__ PA, const ushort_t* __restrict__ PB,
    const float* __restrict__ W_ifT, const float* __restrict__ b_ifF,
    u64* GH0, u64* GH1, u64* GLR, unsigned* FL,
    bf16* __restrict__ cat)
{
  const int q   = blockIdx.x;
  const int tid = threadIdx.x;
  const int wv  = tid>>6, l = tid&63;
  const int lm  = l&15,  quad = l>>4;
  const int rt  = wv&1,  kh = wv>>1;
  const int f32i = flags[0];

  __shared__ u64  HBuf[2][2048];
  __shared__ float preact[32*65];
  __shared__ float oc[512];
  __shared__ float b1L[32];
  __shared__ float xis[136], xpart[3*136];
  __shared__ float s_mem[80], s_mem2[80], s_link[25], s_link2[25];
  __shared__ float s_prec[5], s_prec2[5], s_rwp[20], s_rw[20];
  __shared__ float s_wwp[5], s_ww[5], s_usage[5], s_wl[5];
  __shared__ float s_rl[20], s_fwd[20], s_bwd[20], s_wsum;
  __shared__ float rvbuf[64];

#define WAITF(TGT) do{ if(tid<64){ unsigned _tg=(unsigned)(TGT); int _wd=0; \
    while(ald32(&FL[tid*1088+135]) < _tg && _wd<50000000){ __builtin_amdgcn_s_sleep(1); _wd++; } } \
  __syncthreads(); }while(0)
#define PUBF(VAL) do{ __syncthreads(); \
  if(tid==0) ast32(&FL[q*1088+135],(unsigned)(VAL)); }while(0)

  // resident weight fragments
  f16x8 fa[5], fb[8];
  {
    const uint4* PAv=(const uint4*)PA;
    const uint4* PBv=(const uint4*)PB;
    #pragma unroll
    for(int c=0;c<5;c++){ U4H8 t4; t4.u = PAv[((q*8+wv)*5+c)*64 + l]; fa[c]=t4.h; }
    #pragma unroll
    for(int c=0;c<8;c++){ U4H8 t4; t4.u = PBv[((q*8+wv)*8+c)*64 + l]; fb[c]=t4.h; }
  }
  if(tid<32){ int g=tid>>3,u=tid&7; b1L[tid]=ldf(b1,(g<<9)+(q<<3)+u,f32i); }
  if(tid<80) s_mem[tid]=0.f;
  if(tid>=128&&tid<153) s_link[tid-128]=0.f;
  if(tid>=160&&tid<165) s_prec[tid-160]=0.f;
  if(tid>=192&&tid<212) s_rwp[tid-192]=0.f;
  if(tid>=224&&tid<229) s_wwp[tid-224]=0.f;
  if(tid>=256&&tid<261) s_usage[tid-256]=0.f;
  if(tid<128){ ast64(&GH0[8192 + (q*64+(tid>>1))*2 + (tid&1)], 0ull);
               ast64(&GH1[8192 + (q*64+(tid>>1))*2 + (tid&1)], 0ull); }
  if(tid<16){  ast64(&GLR[1024 + ((tid>>1)*64+q)*2 + (tid&1)], 0ull); }
  float c0s[8], c1s[8];
  #pragma unroll
  for(int u=0;u<8;u++){ c0s[u]=0.f; c1s[u]=0.f; }

  // init barrier: flag=1 doubles as gamma(-1) for the t=0 wait.
  PUBF(1u);
  WAITF(1u);

  for(int t=0;t<512;t++){
    const int p=t&1, pm=p^1;

    // ====== A(t) part1: 16 h0(t-1)-chunks (alpha(t-1) already passed) ======
    u64 ra[16];
    #pragma unroll
    for(int i=0;i<16;i++) ra[i]=ald64(&GH0[pm*8192 + tid + 512*i]);
    float em[4][8];
    if(wv==0){
      int tokb = tokens[l*512+t];
      #pragma unroll
      for(int g=0;g<4;g++)
        #pragma unroll
        for(int u=0;u<8;u++)
          em[g][u]=embW[((g<<9)+(q<<3)+u)*256 + tokb];
    }
    for(int i=tid;i<2080;i+=512) preact[i]=0.f;
    f32x4 acc[4];
    #pragma unroll
    for(int bt=0;bt<4;bt++) acc[bt]=(f32x4){0.f,0.f,0.f,0.f};
    #pragma unroll
    for(int blk=0;blk<4;blk++){
      #pragma unroll
      for(int jj=0;jj<4;jj++) HBuf[blk&1][tid+512*jj]=ra[blk*4+jj];
      __syncthreads();
      const f16x8* hb=(const f16x8*)(&HBuf[blk&1][0]);
      #pragma unroll
      for(int bt=0;bt<4;bt++){
        f16x8 bfr = hb[(kh*4+quad)*64 + bt*16 + lm];
        acc[bt]=__builtin_amdgcn_mfma_f32_16x16x32_f16(fa[blk],bfr,acc[bt],0,0,0);
      }
    }

    // ====== wait gamma(t-1): lr(t-1) ======
    WAITF(3*t+1);

    // ====== A(t) part2: lr chunk, reduce, nonlinearity ======
    {
      u64 rg0=ald64(&GLR[pm*1024 + tid]);
      u64 rg1=ald64(&GLR[pm*1024 + tid + 512]);
      HBuf[0][tid]=rg0; HBuf[0][tid+512]=rg1;
      __syncthreads();
      if(kh<2){
        const f16x8* hb=(const f16x8*)(&HBuf[0][0]);
        #pragma unroll
        for(int bt=0;bt<4;bt++){
          f16x8 bfr = hb[(kh*4+quad)*64 + bt*16 + lm];
          acc[bt]=__builtin_amdgcn_mfma_f32_16x16x32_f16(fa[4],bfr,acc[bt],0,0,0);
        }
      }
    }
    #pragma unroll
    for(int bt=0;bt<4;bt++)
      #pragma unroll
      for(int r=0;r<4;r++)
        atomicAdd(&preact[(rt*16+quad*4+r)*65 + bt*16 + lm], acc[bt][r]);
    __syncthreads();
    if(wv==0){
      U64H4 pk0, pk1;
      #pragma unroll
      for(int u=0;u<8;u++){
        float gi=preact[(u   )*65+l]+em[0][u];
        float gf=preact[(8+u )*65+l]+em[1][u];
        float gg=preact[(16+u)*65+l]+em[2][u];
        float go=preact[(24+u)*65+l]+em[3][u];
        float c=sigf(gf)*c0s[u]+sigf(gi)*tanhf(gg);
        c0s[u]=c;
        float h=sigf(go)*tanhf(c);
        if(u<4) pk0.h[u]=(f16)h; else pk1.h[u-4]=(f16)h;
      }
      ast64(&GH0[p*8192+(q*64+l)*2  ], pk0.u);
      ast64(&GH0[p*8192+(q*64+l)*2+1], pk1.u);
    }
    PUBF(3*t+2);     // alpha(t)

    // ====== B(t) part1: 16 h1(t-1)-chunks (beta(t-1) already passed) ======
    u64 rb1[16];
    #pragma unroll
    for(int i=0;i<16;i++) rb1[i]=ald64(&GH1[pm*8192 + tid + 512*(i-0)]);
    for(int i=tid;i<2080;i+=512) preact[i]=0.f;
    #pragma unroll
    for(int bt=0;bt<4;bt++) acc[bt]=(f32x4){0.f,0.f,0.f,0.f};
    #pragma unroll
    for(int blk=4;blk<8;blk++){
      #pragma unroll
      for(int jj=0;jj<4;jj++) HBuf[blk&1][tid+512*jj]=rb1[(blk-4)*4+jj];
      __syncthreads();
      const f16x8* hb=(const f16x8*)(&HBuf[blk&1][0]);
      #pragma unroll
      for(int bt=0;bt<4;bt++){
        f16x8 bfr = hb[(kh*4+quad)*64 + bt*16 + lm];
        acc[bt]=__builtin_amdgcn_mfma_f32_16x16x32_f16(fb[blk],bfr,acc[bt],0,0,0);
      }
    }

    // ====== wait alpha(t): h0(t) from all blocks ======
    WAITF(3*t+2);

    // ====== B(t) part2: 16 h0(t)-chunks, reduce, nonlinearity ======
    u64 rb0[16];
    #pragma unroll
    for(int i=0;i<16;i++) rb0[i]=ald64(&GH0[p*8192 + tid + 512*i]);
    #pragma unroll
    for(int blk=0;blk<4;blk++){
      #pragma unroll
      for(int jj=0;jj<4;jj++) HBuf[blk&1][tid+512*jj]=rb0[blk*4+jj];
      __syncthreads();
      const f16x8* hb=(const f16x8*)(&HBuf[blk&1][0]);
      #pragma unroll
      for(int bt=0;bt<4;bt++){
        f16x8 bfr = hb[(kh*4+quad)*64 + bt*16 + lm];
        acc[bt]=__builtin_amdgcn_mfma_f32_16x16x32_f16(fb[blk],bfr,acc[bt],0,0,0);
      }
    }
    #pragma unroll
    for(int bt=0;bt<4;bt++)
      #pragma unroll
      for(int r=0;r<4;r++)
        atomicAdd(&preact[(rt*16+quad*4+r)*65 + bt*16 + lm], acc[bt][r]);
    __syncthreads();
    if(wv==0){
      U64H4 pk0, pk1;
      #pragma unroll
      for(int u=0;u<8;u++){
        float gi=preact[(u   )*65+l]+b1L[u];
        float gf=preact[(8+u )*65+l]+b1L[8+u];
        float gg=preact[(16+u)*65+l]+b1L[16+u];
        float go=preact[(24+u)*65+l]+b1L[24+u];
        float c=sigf(gf)*c1s[u]+sigf(gi)*tanhf(gg);
        c1s[u]=c;
        float h=sigf(go)*tanhf(c);
        if(u<4) pk0.h[u]=(f16)h; else pk1.h[u-4]=(f16)h;
      }
      ast64(&GH1[p*8192+(q*64+l)*2  ], pk0.u);
      ast64(&GH1[p*8192+(q*64+l)*2+1], pk1.u);
    }
    PUBF(3*t+3);     // beta(t)

    // ====== wait beta(t): h1(t) from all blocks ======
    WAITF(3*t+3);

    // ====== P3(t): DNC machinery for batch q ======
    if(tid<128){
      int g=tid>>1, hh=tid&1;
      U64H4 pv; pv.u=ald64(&GH1[p*8192+(g*64+q)*2+hh]);
      #pragma unroll
      for(int jj=0;jj<4;jj++){
        int k=g*8+hh*4+jj;
        float x=(float)pv.h[jj];
        x=fminf(fmaxf(x,-20.f),20.f);
        oc[k]=x;
        cat[(q*512+t)*576+k]=__float2bfloat16(x);
      }
    }
    __syncthreads();
    if(tid<405){
      int qq=tid/135, v=tid-qq*135;
      int k0=qq*171, k1=k0+171; if(k1>512)k1=512;
      float a=0.f;
      for(int k=k0;k<k1;k++) a += oc[k]*W_ifT[k*136+v];
      xpart[qq*136+v]=a;
    }
    __syncthreads();
    if(tid<135) xis[tid]=b_ifF[tid]+xpart[tid]+xpart[136+tid]+xpart[272+tid];
    __syncthreads();
    if(tid<5){
      int m=tid;
      float u=s_usage[m]+(1.f-s_usage[m])*s_wwp[m];
      float psi=1.f;
      #pragma unroll
      for(int r=0;r<4;r++) psi *= 1.f - sigf(xis[117+r])*s_rwp[r*5+m];
      u*=psi; s_usage[m]=u;
      float nm=0.f,dt=0.f,nk=0.f;
      #pragma unroll
      for(int w=0;w<16;w++){
        float mv=s_mem[m*16+w], kv=tanhf(xis[68+w]);
        nm+=mv*mv; dt+=mv*kv; nk+=kv*kv;
      }
      float sim=dt/((sqrtf(nm)+1e-6f)*(sqrtf(nk)+1e-6f));
      s_wl[m]=sim*splus(xis[84]);
    }
    __syncthreads();
    if(tid==0){
      float mx=-1e30f;
      for(int m=0;m<5;m++) mx=fmaxf(mx,s_wl[m]);
      float e[5]; float s=0.f;
      for(int m=0;m<5;m++){ e[m]=expf(s_wl[m]-mx); s+=e[m]; }
      float u[5]; int id[5];
      for(int m=0;m<5;m++){ u[m]=1e-6f+(1.f-1e-6f)*s_usage[m]; id[m]=m; }
      for(int i=1;i<5;i++){
        float uv=u[i]; int iv=id[i]; int j=i-1;
        while(j>=0&&u[j]>uv){u[j+1]=u[j];id[j+1]=id[j];j--;}
        u[j+1]=uv; id[j+1]=iv;
      }
      float alm[5]; float prod=1.f;
      for(int i=0;i<5;i++){ alm[id[i]]=(1.f-u[i])*prod; prod*=u[i]; }
      float ag=sigf(xis[121]), wgg=sigf(xis[122]);
      float wsum=0.f;
      for(int m=0;m<5;m++){
        float wcw=e[m]/s;
        float w_=wgg*(ag*alm[m]+(1.f-ag)*wcw);
        s_ww[m]=w_; wsum+=w_;
      }
      s_wsum=wsum;
    }
    __syncthreads();
    if(tid<80){
      int m=tid>>4,w=tid&15;
      float er=sigf(xis[85+w]), wvv=tanhf(xis[101+w]);
      float w_=s_ww[m];
      s_mem2[tid]=s_mem[tid]*(1.f-w_*er)+w_*wvv;
    } else if(tid>=128&&tid<153){
      int qq=tid-128; int i=qq/5, j=qq-5*i;
      s_link2[qq]=(i==j)?0.f:((1.f-s_ww[i]-s_ww[j])*s_link[qq]+s_ww[i]*s_prec[j]);
    } else if(tid>=160&&tid<165){
      int j=tid-160;
      s_prec2[j]=(1.f-s_wsum)*s_prec[j]+s_ww[j];
    }
    __syncthreads();
    if(tid<20){
      int r=tid/5,m=tid-5*(tid/5);
      float nm=0.f,dt=0.f,nk=0.f;
      #pragma unroll
      for(int w=0;w<16;w++){
        float mv=s_mem2[m*16+w], kv=tanhf(xis[r*16+w]);
        nm+=mv*mv; dt+=mv*kv; nk+=kv*kv;
      }
      float sim=dt/((sqrtf(nm)+1e-6f)*(sqrtf(nk)+1e-6f));
      s_rl[tid]=sim*splus(xis[64+r]);
    } else if(tid>=64&&tid<84){
      int qq=tid-64; int r=qq/5, i=qq-5*r;
      float a=0.f;
      #pragma unroll
      for(int j=0;j<5;j++) a+=s_link2[i*5+j]*s_rwp[r*5+j];
      s_fwd[r*5+i]=a;
    } else if(tid>=96&&tid<116){
      int qq=tid-96; int r=qq/5, j=qq-5*r;
      float a=0.f;
      #pragma unroll
      for(int i=0;i<5;i++) a+=s_link2[i*5+j]*s_rwp[r*5+i];
      s_bwd[r*5+j]=a;
    }
    __syncthreads();
    if(tid<20){
      int r=tid/5;
      float mx=-1e30f;
      for(int m=0;m<5;m++) mx=fmaxf(mx,s_rl[r*5+m]);
      float s=0.f;
      for(int m=0;m<5;m++) s+=expf(s_rl[r*5+m]-mx);
      float rcw=expf(s_rl[tid]-mx)/s;
      float q0=xis[123+3*r],q1=xis[124+3*r],q2=xis[125+3*r];
      float m3=fmaxf(q0,fmaxf(q1,q2));
      float e0=expf(q0-m3),e1=expf(q1-m3),e2=expf(q2-m3);
      float inv=1.f/(e0+e1+e2);
      s_rw[tid]=(e0*s_bwd[tid]+e1*s_fwd[tid]+e2*rcw)*inv;
    }
    __syncthreads();
    if(tid<64){
      int r=tid>>4,w=tid&15;
      float a=0.f;
      #pragma unroll
      for(int m=0;m<5;m++) a+=s_rw[r*5+m]*s_mem2[m*16+w];
      rvbuf[tid]=a;
    } else if(tid>=128&&tid<208){ s_mem [tid-128]=s_mem2 [tid-128];
    } else if(tid>=208&&tid<233){ s_link[tid-208]=s_link2[tid-208];
    } else if(tid>=240&&tid<245){ s_prec[tid-240]=s_prec2[tid-240];
    } else if(tid>=256&&tid<276){ s_rwp [tid-256]=s_rw   [tid-256];
    } else if(tid>=288&&tid<293){ s_wwp [tid-288]=s_ww   [tid-288]; }
    __syncthreads();
    if(tid<32){
      U32H2 pk; pk.h[0]=(f16)rvbuf[2*tid]; pk.h[1]=(f16)rvbuf[2*tid+1];
      ast32(&((unsigned*)GLR)[p*2048 + ((tid>>2)*64+q)*4 + (tid&3)], pk.u);
    }
    PUBF(3*t+4);     // gamma(t) — other blocks can start A(t+1) part2

    // post-publish (off critical path): cat read-vector slice
    if(tid<64) cat[(q*512+t)*576+512+tid]=__float2bfloat16(rvbuf[tid]);
  }
#undef WAITF
#undef PUBF
}

// ---------------- final output GEMM (f32 out) ----------------
__global__ void __launch_bounds__(256) k_out(const bf16* __restrict__ cat,
                                             const float* __restrict__ Wc,
                                             const float* __restrict__ bc,
                                             float* __restrict__ outp){
  int t0=blockIdx.x*64, v0=blockIdx.y*64, b=blockIdx.z;
  __shared__ float As[64][33];
  __shared__ float Bs[32][65];
  int tid=threadIdx.x;
  int ti=tid>>4, vi=tid&15;
  float acc[4][4]={};
  for(int k0=0;k0<576;k0+=32){
    for(int i=tid;i<64*32;i+=256){
      int r=i>>5,k=i&31;
      As[r][k]=b2f(cat[(b*512+t0+r)*576+k0+k]);
    }
    for(int i=tid;i<64*32;i+=256){
      int v=i>>5,k=i&31;
      Bs[k][v]=Wc[(v0+v)*576+k0+k];
    }
    __syncthreads();
    #pragma unroll 8
    for(int kk=0;kk<32;kk++){
      float av[4],bv[4];
      #pragma unroll
      for(int x=0;x<4;x++) av[x]=As[ti*4+x][kk];
      #pragma unroll
      for(int y=0;y<4;y++) bv[y]=Bs[kk][vi*4+y];
      #pragma unroll
      for(int x=0;x<4;x++)
        #pragma unroll
        for(int y=0;y<4;y++) acc[x][y]+=av[x]*bv[y];
    }
    __syncthreads();
  }
  #pragma unroll
  for(int y=0;y<4;y++){
    int v=v0+vi*4+y;
    float bcv=bc[v];
    #pragma unroll
    for(int x=0;x<4;x++){
      int tt=t0+ti*4+x;
      outp[(b*256+v)*512+tt]=acc[x][y]+bcv;
    }
  }
}

extern "C" void kernel_launch(void* const* d_in, const int* in_sizes, int n_in,
                              void* d_out, int out_size, void* d_ws, size_t ws_size,
                              hipStream_t stream) {
  const int*  tokens = (const int*) d_in[0];
  const void* emb    = d_in[1];
  const void* Wi0    = d_in[2];
  const void* Wh0    = d_in[3];
  const void* b0     = d_in[4];
  const void* Wi1    = d_in[5];
  const void* Wh1    = d_in[6];
  const void* b1     = d_in[7];
  const void* W_if   = d_in[8];
  const void* b_if   = d_in[9];
  const void* W_out  = d_in[10];
  const void* b_out  = d_in[11];
  const void* W_fc   = d_in[12];
  const void* b_fc   = d_in[13];

  static const int expect[14] = {64*512, 256*512, 2048*576, 2048*512, 2048,
                                 2048*512, 2048*512, 2048, 135*512, 135,
                                 512*576, 512, 256*512, 256};
  bool ok = (n_in == 14);
  if(ok) for(int i=0;i<14;i++) if(in_sizes[i]!=expect[i]) ok=false;

  int*      flags = (int*)d_ws;                   // [0]=dtype flag
  float*    embW  = (float*)d_ws + 64;            // 2048*256
  ushort_t* PA    = (ushort_t*)(embW + 524288);   // 1310720 f16
  ushort_t* PB    = PA + 1310720;                 // 2097152 f16
  float*    W_ifT = (float*)(PB + 2097152);       // 69632 (pad col 135 = flags)
  float*    b_ifF = W_ifT + 69632;                // 160
  float*    Wc    = b_ifF + 160;                  // 147456
  float*    bc    = Wc + 147456;                  // 256
  u64*      GH0   = (u64*)(bc + 256);             // 2*8192
  u64*      GH1   = GH0 + 16384;                  // 2*8192
  u64*      GLR   = GH1 + 16384;                  // 2*1024
  bf16*     cat   = (bf16*)(GLR + 2048);          // 64*512*576
  unsigned* FL    = (unsigned*)W_ifT;             // flags live in pad column

  size_t need = 9783168ull + 278528ull + 37748736ull;   // = 47,810,432 B
  if(!ok || ws_size < need){
    hipMemsetAsync(d_out, 0, (size_t)out_size*4, stream);
    return;
  }

  k_detect<<<dim3(1), dim3(256), 0, stream>>>(emb, flags);
  k_embW<<<dim3(2048), dim3(256), 0, stream>>>(emb, Wi0, b0, flags, embW);
  k_wpkA<<<dim3(5120), dim3(256), 0, stream>>>(Wh0, Wi0, flags, PA);
  k_wpkB<<<dim3(8192), dim3(256), 0, stream>>>(Wi1, Wh1, flags, PB);
  k_wifT<<<dim3((135*512+255)/256), dim3(256), 0, stream>>>(W_if, b_if, flags, W_ifT, b_ifF);
  k_wc  <<<dim3(576),  dim3(256), 0, stream>>>(W_fc, W_out, b_out, b_fc, flags, Wc, bc);

  void* kargs[] = {
    (void*)&tokens, (void*)&b1, (void*)&flags,
    (void*)&embW, (void*)&PA, (void*)&PB,
    (void*)&W_ifT, (void*)&b_ifF,
    (void*)&GH0, (void*)&GH1, (void*)&GLR, (void*)&FL,
    (void*)&cat
  };
  hipLaunchCooperativeKernel((const void*)k_dnc3, dim3(64), dim3(512), kargs, 0, stream);

  k_out<<<dim3(8,4,64), dim3(256), 0, stream>>>(cat, Wc, bc, (float*)d_out);
}

// Round 3
// 18699.477 us; speedup vs baseline: 1.7473x; 1.6188x over previous
//
#include <hip/hip_runtime.h>
#include <hip/hip_bf16.h>

typedef __hip_bfloat16 bf16;
typedef _Float16 f16;
typedef _Float16 f16x8 __attribute__((ext_vector_type(8)));
typedef float f32x4 __attribute__((ext_vector_type(4)));
typedef unsigned long long u64;
typedef unsigned short ushort_t;

__device__ __forceinline__ float b2f(bf16 x){ return __bfloat162float(x); }
__device__ __forceinline__ float sigf(float x){ return 1.f/(1.f+expf(-x)); }
__device__ __forceinline__ float splus(float x){ return fmaxf(x,0.f)+log1pf(expf(-fabsf(x))); }
__device__ __forceinline__ float ldf(const void* p, int i, int isf32){
  return isf32 ? ((const float*)p)[i] : __bfloat162float(((const bf16*)p)[i]);
}
// agent-scope coherent ops (bypass per-XCD L2). Proven cross-XCD coherent, no fences.
__device__ __forceinline__ void ast64(u64* p, u64 v){ __hip_atomic_store(p, v, __ATOMIC_RELAXED, __HIP_MEMORY_SCOPE_AGENT); }
__device__ __forceinline__ u64 ald64(u64* p){ return __hip_atomic_load(p, __ATOMIC_RELAXED, __HIP_MEMORY_SCOPE_AGENT); }
__device__ __forceinline__ void ast32(unsigned* p, unsigned v){ __hip_atomic_store(p, v, __ATOMIC_RELAXED, __HIP_MEMORY_SCOPE_AGENT); }
__device__ __forceinline__ unsigned ald32(unsigned* p){ return __hip_atomic_load(p, __ATOMIC_RELAXED, __HIP_MEMORY_SCOPE_AGENT); }

union U4H8 { uint4 u; f16x8 h; };
union U64H4 { u64 u; f16 h[4]; };
union H16 { f16 h; ushort_t s; };

// ---------------- dtype detect ----------------
__global__ void k_detect(const void* __restrict__ emb, int* __restrict__ flag){
  __shared__ float mx[256];
  int tid=threadIdx.x;
  float v = fabsf(__bfloat162float(((const bf16*)emb)[tid]));
  mx[tid]=v; __syncthreads();
  for(int s=128;s>0;s>>=1){ if(tid<s) mx[tid]=fmaxf(mx[tid],mx[tid+s]); __syncthreads(); }
  if(tid==0){ flag[0] = (mx[0]>1000.f) ? 1 : 0; flag[1] = 0; }
}

// ---------------- setup ----------------
// embW[row][v] = b0[row] + sum_k emb[v][k]*Wi0[row][k]   (row-major [2048][256])
__global__ void k_embW(const void* __restrict__ emb, const void* __restrict__ Wi0,
                       const void* __restrict__ b0,
                       const int* __restrict__ flags, float* __restrict__ embW){
  int f=flags[0];
  int row = blockIdx.x;
  __shared__ float w[512];
  for(int k=threadIdx.x;k<512;k+=256) w[k]=ldf(Wi0,row*576+k,f);
  __syncthreads();
  int v = threadIdx.x;
  float acc=ldf(b0,row,f);
  #pragma unroll 4
  for(int k=0;k<512;k++) acc += ldf(emb,v*512+k,f)*w[k];
  embW[row*256+v]=acc;
}

// ---- weight prepack for the group design ----
// Block (g,r): r in [0,16) owns 32 hidden dims D_r=[32r,32r+32) -> 128 gate rows.
// Wave w = G*2+h (G=gate 0..3, h=half) owns rows G*512 + r*32 + h*16 + [0,16).
// A-frag (16x16x32 f16): lane l holds row (l&15), k = (l>>4)*8 + j.
// PA[(((r*8+w)*18+c)*64+l)*8+j], c = k-chunk (18 chunks: k<512 Wh0, k>=512 Wi0 lr cols).
__global__ void k_wpkA(const void* __restrict__ Wh0, const void* __restrict__ Wi0,
                       const int* __restrict__ flags, ushort_t* __restrict__ PA){
  int f=flags[0];
  int idx=blockIdx.x*256+threadIdx.x;
  if(idx>=1179648) return;
  int j=idx&7, l=(idx>>3)&63, rest=idx>>9;
  int c=rest%18, t2=rest/18, w=t2&7, r=t2>>3;
  int G=w>>1, hh=w&1, m=l&15, q4=l>>4;
  int row=G*512 + r*32 + hh*16 + m;
  int k=c*32 + q4*8 + j;
  float val = (k<512)? ldf(Wh0,row*512+k,f) : ldf(Wi0,row*576+k,f);
  H16 hx; hx.h=(f16)val; PA[idx]=hx.s;
}
// PB[(((r*8+w)*32+c)*64+l)*8+j], 32 chunks: k<512 Wi1 (h0(t) input), k>=512 Wh1 (h1(t-1)).
__global__ void k_wpkB(const void* __restrict__ Wi1, const void* __restrict__ Wh1,
                       const int* __restrict__ flags, ushort_t* __restrict__ PB){
  int f=flags[0];
  int idx=blockIdx.x*256+threadIdx.x;
  if(idx>=2097152) return;
  int j=idx&7, l=(idx>>3)&63, rest=idx>>9;
  int c=rest&31, t2=rest>>5, w=t2&7, r=t2>>3;
  int G=w>>1, hh=w&1, m=l&15, q4=l>>4;
  int row=G*512 + r*32 + hh*16 + m;
  int k=c*32 + q4*8 + j;
  float val = (k<512)? ldf(Wi1,row*512+k,f) : ldf(Wh1,row*512+k-512,f);
  H16 hx; hx.h=(f16)val; PB[idx]=hx.s;
}

// W_ifT [512][136]; pad column 135 = per-block sync flags (zeroed here).
__global__ void k_wifT(const void* __restrict__ W_if, const void* __restrict__ b_if,
                       const int* __restrict__ flags,
                       float* __restrict__ W_ifT, float* __restrict__ b_ifF){
  int f=flags[0];
  int idx=blockIdx.x*256+threadIdx.x;
  if(idx<135*512){ int v=idx/512, k=idx-v*512; W_ifT[k*136+v]=ldf(W_if,idx,f); }
  if(idx<512) W_ifT[idx*136+135]=0.f;
  if(idx<135) b_ifF[idx]=ldf(b_if,idx,f);
}

__global__ void k_wc(const void* __restrict__ W_fc, const void* __restrict__ W_out,
                     const void* __restrict__ b_out, const void* __restrict__ b_fc,
                     const int* __restrict__ flags,
                     float* __restrict__ Wc, float* __restrict__ bc){
  int f=flags[0];
  int idx=blockIdx.x*256+threadIdx.x;
  int v=idx/576, j=idx-v*576;
  float acc=0.f;
  #pragma unroll 4
  for(int d=0;d<512;d++) acc += ldf(W_fc,v*512+d,f)*ldf(W_out,d*576+j,f);
  Wc[idx]=acc;
  if(j==0){
    float a=ldf(b_fc,v,f);
    for(int d=0;d<512;d++) a += ldf(W_fc,v*512+d,f)*ldf(b_out,d,f);
    bc[v]=a;
  }
}

// ---------------- grouped recurrence: 4 independent groups x 16 blocks ----------------
// Group g owns batches [16g,16g+16). Block (g,r) owns hidden dims [32r,32r+32),
// holds its 425KB weight slice in VGPRs (fa[18]+fb[32] f16x8 frags), and runs
// the DNC machinery (P3) for batch 16g+r.
// Exchange per group via agent-scope LLC buffers (double-buffered by t&1):
//   GX0 = h0 slices (u64 slot (kg*16+b)*2+e; kg=dim>>3), GX1 = h1, GXL = lr (8 kg).
// Flag protocol per block (monotone, in W_ifT pad col): init->1, alpha(t)->3t+2,
// beta(t)->3t+3, gamma(t)->3t+4. Waits poll only the 16 group flags.
// Publish = syncthreads (vmcnt(0) drain for all waves) then tid0 flag store;
// same ordering as the harness-proven scheme. Buffer-overwrite safety under the
// skew re-verified: every overwrite of a phase buffer is flag-chain-ordered
// after all readers of its previous contents (A-part1 reads of GX0[p] old
// content precede that block's gamma(t-1), which gates the alpha(t) writers, etc).
__global__ void __launch_bounds__(512,2) k_dnc3(
    const int* __restrict__ tokens, const void* __restrict__ b1, const int* __restrict__ flags,
    const float* __restrict__ embW, const ushort_t* __restrict__ PA, const ushort_t* __restrict__ PB,
    const float* __restrict__ W_ifT, const float* __restrict__ b_ifF,
    u64* GX0, u64* GX1, u64* GXL, unsigned* FL,
    bf16* __restrict__ cat)
{
  const int bid = blockIdx.x;
  const int g   = bid>>4, r = bid&15;
  const int tid = threadIdx.x;
  const int wv  = tid>>6, l = tid&63;
  const int lm  = l&15,  q4 = l>>4;
  const int d   = tid>>4, bb = tid&15;     // nonlinearity mapping: dim, batch
  const int f32i = flags[0];

  __shared__ __align__(16) u64 LBA[2304];   // layer A B-operand: kg 0..63 h0prev, 64..71 lr
  __shared__ __align__(16) u64 LBB[4096];   // layer B: kg 0..63 h0(t), 64..127 h1(t-1)
  __shared__ float PR[128*17];              // preact exchange [local row][batch]
  __shared__ f16  sh_pub[512];              // h slice [d*16+b]
  __shared__ float sh_b1[128];
  __shared__ float oc[512];
  __shared__ int  tokLDS[16];
  __shared__ float xis[136], xpart[3*136];
  __shared__ float s_mem[80], s_mem2[80], s_link[25], s_link2[25];
  __shared__ float s_prec[5], s_prec2[5], s_rwp[20], s_rw[20];
  __shared__ float s_wwp[5], s_ww[5], s_usage[5], s_wl[5];
  __shared__ float s_rl[20], s_fwd[20], s_bwd[20], s_wsum;
  __shared__ float rvbuf[64];

#define WAITG(TGT) do{ if(tid<16){ unsigned _tg=(unsigned)(TGT); int _wd=0; \
    while(ald32(&FL[(g*16+tid)*1088+135]) < _tg && _wd<50000000){ __builtin_amdgcn_s_sleep(1); _wd++; } } \
  __syncthreads(); }while(0)
#define PUBF(VAL) do{ __syncthreads(); \
  if(tid==0) ast32(&FL[bid*1088+135],(unsigned)(VAL)); }while(0)

  // resident weight fragments (~200 VGPR)
  f16x8 fa[18], fb[32];
  {
    const uint4* PAv=(const uint4*)PA;
    const uint4* PBv=(const uint4*)PB;
    #pragma unroll
    for(int c=0;c<18;c++){ U4H8 t4; t4.u = PAv[((r*8+wv)*18+c)*64 + l]; fa[c]=t4.h; }
    #pragma unroll
    for(int c=0;c<32;c++){ U4H8 t4; t4.u = PBv[((r*8+wv)*32+c)*64 + l]; fb[c]=t4.h; }
  }
  if(tid<128) sh_b1[tid]=ldf(b1,(tid>>5)*512 + r*32 + (tid&31), f32i);
  if(tid<80) s_mem[tid]=0.f;
  if(tid>=128&&tid<153) s_link[tid-128]=0.f;
  if(tid>=160&&tid<165) s_prec[tid-160]=0.f;
  if(tid>=192&&tid<212) s_rwp[tid-192]=0.f;
  if(tid>=224&&tid<229) s_wwp[tid-224]=0.f;
  if(tid>=256&&tid<261) s_usage[tid-256]=0.f;
  // zero phase-1 exchange slots this block owns (t=0 reads pm=1)
  if(tid<128){
    int ks=tid>>4, b2=tid&15;
    int slot=((4*r+(ks>>1))*16+b2)*2+(ks&1);
    ast64(&GX0[g*4096+2048+slot],0ull);
    ast64(&GX1[g*4096+2048+slot],0ull);
  }
  if(tid<16) ast64(&GXL[g*512+256+((tid>>1)*16+r)*2+(tid&1)],0ull);
  float c0s=0.f, c1s=0.f;

  PUBF(1u);      // init: doubles as gamma(-1)
  WAITG(1u);

  const f16x8* LBAv=(const f16x8*)LBA;
  const f16x8* LBBv=(const f16x8*)LBB;

  for(int t=0;t<512;t++){
    const int p=t&1, pm=p^1;

    // ====== A(t): stage h0(t-1) [alpha(t-1) already passed] ======
    if(tid<16) tokLDS[tid]=tokens[(g*16+tid)*512+t];
    {
      u64 st0=ald64(&GX0[g*4096+pm*2048+tid      ]);
      u64 st1=ald64(&GX0[g*4096+pm*2048+tid+512  ]);
      u64 st2=ald64(&GX0[g*4096+pm*2048+tid+1024 ]);
      u64 st3=ald64(&GX0[g*4096+pm*2048+tid+1536 ]);
      LBA[tid]=st0; LBA[tid+512]=st1; LBA[tid+1024]=st2; LBA[tid+1536]=st3;
    }
    __syncthreads();                                   // S1: LBA h0prev + tokens
    float em0,em1,em2,em3;
    {
      int tok=tokLDS[bb];
      int base=(r*32+d)*256+tok;
      em0=embW[base]; em1=embW[131072+base]; em2=embW[262144+base]; em3=embW[393216+base];
    }
    f32x4 acc=(f32x4){0.f,0.f,0.f,0.f};
    #pragma unroll
    for(int c=0;c<16;c++){
      f16x8 bfr=LBAv[(c*4+q4)*16+lm];
      acc=__builtin_amdgcn_mfma_f32_16x16x32_f16(fa[c],bfr,acc,0,0,0);
    }
    WAITG(3*t+1);                                      // gamma(t-1): lr ready
    if(tid<256) LBA[2048+tid]=ald64(&GXL[g*512+pm*256+tid]);
    __syncthreads();                                   // S2
    #pragma unroll
    for(int c=16;c<18;c++){
      f16x8 bfr=LBAv[(c*4+q4)*16+lm];
      acc=__builtin_amdgcn_mfma_f32_16x16x32_f16(fa[c],bfr,acc,0,0,0);
    }
    #pragma unroll
    for(int reg=0;reg<4;reg++) PR[(wv*16+q4*4+reg)*17+lm]=acc[reg];
    __syncthreads();                                   // S3
    {
      float gi=PR[(d     )*17+bb]+em0;
      float gf=PR[(32+d  )*17+bb]+em1;
      float gg=PR[(64+d  )*17+bb]+em2;
      float go=PR[(96+d  )*17+bb]+em3;
      float c0=sigf(gf)*c0s+sigf(gi)*tanhf(gg);
      c0s=c0;
      float h=sigf(go)*tanhf(c0);
      sh_pub[d*16+bb]=(f16)h;
    }
    __syncthreads();                                   // S4
    if(tid<128){
      int ks=tid>>4, b2=tid&15;
      U64H4 pk;
      #pragma unroll
      for(int i=0;i<4;i++) pk.h[i]=sh_pub[(ks*4+i)*16+b2];
      ast64(&GX0[g*4096+p*2048+((4*r+(ks>>1))*16+b2)*2+(ks&1)], pk.u);
    }
    PUBF(3*t+2);                                       // alpha(t)

    // ====== B(t): stage h1(t-1) [beta(t-1) passed] ======
    {
      u64 st0=ald64(&GX1[g*4096+pm*2048+tid      ]);
      u64 st1=ald64(&GX1[g*4096+pm*2048+tid+512  ]);
      u64 st2=ald64(&GX1[g*4096+pm*2048+tid+1024 ]);
      u64 st3=ald64(&GX1[g*4096+pm*2048+tid+1536 ]);
      LBB[2048+tid]=st0; LBB[2048+tid+512]=st1; LBB[2048+tid+1024]=st2; LBB[2048+tid+1536]=st3;
    }
    __syncthreads();                                   // S6
    acc=(f32x4){0.f,0.f,0.f,0.f};
    #pragma unroll
    for(int c=16;c<32;c++){
      f16x8 bfr=LBBv[(c*4+q4)*16+lm];
      acc=__builtin_amdgcn_mfma_f32_16x16x32_f16(fb[c],bfr,acc,0,0,0);
    }
    WAITG(3*t+2);                                      // alpha(t): h0(t) ready
    {
      u64 st0=ald64(&GX0[g*4096+p*2048+tid      ]);
      u64 st1=ald64(&GX0[g*4096+p*2048+tid+512  ]);
      u64 st2=ald64(&GX0[g*4096+p*2048+tid+1024 ]);
      u64 st3=ald64(&GX0[g*4096+p*2048+tid+1536 ]);
      LBB[tid]=st0; LBB[tid+512]=st1; LBB[tid+1024]=st2; LBB[tid+1536]=st3;
    }
    __syncthreads();                                   // S7
    #pragma unroll
    for(int c=0;c<16;c++){
      f16x8 bfr=LBBv[(c*4+q4)*16+lm];
      acc=__builtin_amdgcn_mfma_f32_16x16x32_f16(fb[c],bfr,acc,0,0,0);
    }
    #pragma unroll
    for(int reg=0;reg<4;reg++) PR[(wv*16+q4*4+reg)*17+lm]=acc[reg];
    __syncthreads();                                   // S8
    {
      float gi=PR[(d     )*17+bb]+sh_b1[d];
      float gf=PR[(32+d  )*17+bb]+sh_b1[32+d];
      float gg=PR[(64+d  )*17+bb]+sh_b1[64+d];
      float go=PR[(96+d  )*17+bb]+sh_b1[96+d];
      float c1=sigf(gf)*c1s+sigf(gi)*tanhf(gg);
      c1s=c1;
      float h=sigf(go)*tanhf(c1);
      sh_pub[d*16+bb]=(f16)h;
    }
    __syncthreads();                                   // S9
    if(tid<128){
      int ks=tid>>4, b2=tid&15;
      U64H4 pk;
      #pragma unroll
      for(int i=0;i<4;i++) pk.h[i]=sh_pub[(ks*4+i)*16+b2];
      ast64(&GX1[g*4096+p*2048+((4*r+(ks>>1))*16+b2)*2+(ks&1)], pk.u);
    }
    PUBF(3*t+3);                                       // beta(t)

    WAITG(3*t+3);                                      // need all h1 slices

    // ====== P3(t): DNC machinery for batch g*16+r ======
    if(tid<128){
      int kg2=tid>>1, e2=tid&1;
      U64H4 pv; pv.u=ald64(&GX1[g*4096+p*2048+(kg2*16+r)*2+e2]);
      #pragma unroll
      for(int jj=0;jj<4;jj++){
        float x=(float)pv.h[jj];
        x=fminf(fmaxf(x,-20.f),20.f);
        oc[kg2*8+e2*4+jj]=x;
      }
    }
    __syncthreads();
    if(tid<405){
      int qq=tid/135, v=tid-qq*135;
      int k0=qq*171, k1=k0+171; if(k1>512)k1=512;
      float a=0.f;
      for(int k=k0;k<k1;k++) a += oc[k]*W_ifT[k*136+v];
      xpart[qq*136+v]=a;
    }
    __syncthreads();
    if(tid<135) xis[tid]=b_ifF[tid]+xpart[tid]+xpart[136+tid]+xpart[272+tid];
    __syncthreads();
    if(tid<5){
      int m=tid;
      float u=s_usage[m]+(1.f-s_usage[m])*s_wwp[m];
      float psi=1.f;
      #pragma unroll
      for(int rr=0;rr<4;rr++) psi *= 1.f - sigf(xis[117+rr])*s_rwp[rr*5+m];
      u*=psi; s_usage[m]=u;
      float nm=0.f,dt=0.f,nk=0.f;
      #pragma unroll
      for(int w=0;w<16;w++){
        float mv=s_mem[m*16+w], kv=tanhf(xis[68+w]);
        nm+=mv*mv; dt+=mv*kv; nk+=kv*kv;
      }
      float sim=dt/((sqrtf(nm)+1e-6f)*(sqrtf(nk)+1e-6f));
      s_wl[m]=sim*splus(xis[84]);
    }
    __syncthreads();
    if(tid==0){
      float mx=-1e30f;
      for(int m=0;m<5;m++) mx=fmaxf(mx,s_wl[m]);
      float e[5]; float s=0.f;
      for(int m=0;m<5;m++){ e[m]=expf(s_wl[m]-mx); s+=e[m]; }
      float u[5]; int id[5];
      for(int m=0;m<5;m++){ u[m]=1e-6f+(1.f-1e-6f)*s_usage[m]; id[m]=m; }
      for(int i=1;i<5;i++){
        float uv=u[i]; int iv=id[i]; int j=i-1;
        while(j>=0&&u[j]>uv){u[j+1]=u[j];id[j+1]=id[j];j--;}
        u[j+1]=uv; id[j+1]=iv;
      }
      float alm[5]; float prod=1.f;
      for(int i=0;i<5;i++){ alm[id[i]]=(1.f-u[i])*prod; prod*=u[i]; }
      float ag=sigf(xis[121]), wgg=sigf(xis[122]);
      float wsum=0.f;
      for(int m=0;m<5;m++){
        float wcw=e[m]/s;
        float w_=wgg*(ag*alm[m]+(1.f-ag)*wcw);
        s_ww[m]=w_; wsum+=w_;
      }
      s_wsum=wsum;
    }
    __syncthreads();
    if(tid<80){
      int m=tid>>4,w=tid&15;
      float er=sigf(xis[85+w]), wvv=tanhf(xis[101+w]);
      float w_=s_ww[m];
      s_mem2[tid]=s_mem[tid]*(1.f-w_*er)+w_*wvv;
    } else if(tid>=128&&tid<153){
      int qq=tid-128; int i=qq/5, j=qq-5*i;
      s_link2[qq]=(i==j)?0.f:((1.f-s_ww[i]-s_ww[j])*s_link[qq]+s_ww[i]*s_prec[j]);
    } else if(tid>=160&&tid<165){
      int j=tid-160;
      s_prec2[j]=(1.f-s_wsum)*s_prec[j]+s_ww[j];
    }
    __syncthreads();
    if(tid<20){
      int rr=tid/5,m=tid-5*(tid/5);
      float nm=0.f,dt=0.f,nk=0.f;
      #pragma unroll
      for(int w=0;w<16;w++){
        float mv=s_mem2[m*16+w], kv=tanhf(xis[rr*16+w]);
        nm+=mv*mv; dt+=mv*kv; nk+=kv*kv;
      }
      float sim=dt/((sqrtf(nm)+1e-6f)*(sqrtf(nk)+1e-6f));
      s_rl[tid]=sim*splus(xis[64+rr]);
    } else if(tid>=64&&tid<84){
      int qq=tid-64; int rr=qq/5, i=qq-5*rr;
      float a=0.f;
      #pragma unroll
      for(int j=0;j<5;j++) a+=s_link2[i*5+j]*s_rwp[rr*5+j];
      s_fwd[rr*5+i]=a;
    } else if(tid>=96&&tid<116){
      int qq=tid-96; int rr=qq/5, j=qq-5*rr;
      float a=0.f;
      #pragma unroll
      for(int i=0;i<5;i++) a+=s_link2[i*5+j]*s_rwp[rr*5+i];
      s_bwd[rr*5+j]=a;
    }
    __syncthreads();
    if(tid<20){
      int rr=tid/5;
      float mx=-1e30f;
      for(int m=0;m<5;m++) mx=fmaxf(mx,s_rl[rr*5+m]);
      float s=0.f;
      for(int m=0;m<5;m++) s+=expf(s_rl[rr*5+m]-mx);
      float rcw=expf(s_rl[tid]-mx)/s;
      float q0=xis[123+3*rr],q1=xis[124+3*rr],q2=xis[125+3*rr];
      float m3=fmaxf(q0,fmaxf(q1,q2));
      float e0=expf(q0-m3),e1=expf(q1-m3),e2=expf(q2-m3);
      float inv=1.f/(e0+e1+e2);
      s_rw[tid]=(e0*s_bwd[tid]+e1*s_fwd[tid]+e2*rcw)*inv;
    }
    __syncthreads();
    if(tid<64){
      int rr=tid>>4,w=tid&15;
      float a=0.f;
      #pragma unroll
      for(int m=0;m<5;m++) a+=s_rw[rr*5+m]*s_mem2[m*16+w];
      rvbuf[tid]=a;
    } else if(tid>=128&&tid<208){ s_mem [tid-128]=s_mem2 [tid-128];
    } else if(tid>=208&&tid<233){ s_link[tid-208]=s_link2[tid-208];
    } else if(tid>=240&&tid<245){ s_prec[tid-240]=s_prec2[tid-240];
    } else if(tid>=256&&tid<276){ s_rwp [tid-256]=s_rw   [tid-256];
    } else if(tid>=288&&tid<293){ s_wwp [tid-288]=s_ww   [tid-288]; }
    __syncthreads();
    if(tid<16){
      U64H4 pk;
      #pragma unroll
      for(int i=0;i<4;i++) pk.h[i]=(f16)rvbuf[4*tid+i];
      ast64(&GXL[g*512+p*256+((tid>>1)*16+r)*2+(tid&1)], pk.u);
    }
    PUBF(3*t+4);                                       // gamma(t)

    // deferred (off critical path): cat writes for batch g*16+r
    {
      int cb=((g*16+r)*512+t)*576;
      cat[cb+tid]=__float2bfloat16(oc[tid]);
      if(tid<64) cat[cb+512+tid]=__float2bfloat16(rvbuf[tid]);
    }
  }
#undef WAITG
#undef PUBF
}

// ---------------- final output GEMM (f32 out) ----------------
__global__ void __launch_bounds__(256) k_out(const bf16* __restrict__ cat,
                                             const float* __restrict__ Wc,
                                             const float* __restrict__ bc,
                                             float* __restrict__ outp){
  int t0=blockIdx.x*64, v0=blockIdx.y*64, b=blockIdx.z;
  __shared__ float As[64][33];
  __shared__ float Bs[32][65];
  int tid=threadIdx.x;
  int ti=tid>>4, vi=tid&15;
  float acc[4][4]={};
  for(int k0=0;k0<576;k0+=32){
    for(int i=tid;i<64*32;i+=256){
      int rr=i>>5,k=i&31;
      As[rr][k]=b2f(cat[(b*512+t0+rr)*576+k0+k]);
    }
    for(int i=tid;i<64*32;i+=256){
      int v=i>>5,k=i&31;
      Bs[k][v]=Wc[(v0+v)*576+k0+k];
    }
    __syncthreads();
    #pragma unroll 8
    for(int kk=0;kk<32;kk++){
      float av[4],bv[4];
      #pragma unroll
      for(int x=0;x<4;x++) av[x]=As[ti*4+x][kk];
      #pragma unroll
      for(int y=0;y<4;y++) bv[y]=Bs[kk][vi*4+y];
      #pragma unroll
      for(int x=0;x<4;x++)
        #pragma unroll
        for(int y=0;y<4;y++) acc[x][y]+=av[x]*bv[y];
    }
    __syncthreads();
  }
  #pragma unroll
  for(int y=0;y<4;y++){
    int v=v0+vi*4+y;
    float bcv=bc[v];
    #pragma unroll
    for(int x=0;x<4;x++){
      int tt=t0+ti*4+x;
      outp[(b*256+v)*512+tt]=acc[x][y]+bcv;
    }
  }
}

extern "C" void kernel_launch(void* const* d_in, const int* in_sizes, int n_in,
                              void* d_out, int out_size, void* d_ws, size_t ws_size,
                              hipStream_t stream) {
  const int*  tokens = (const int*) d_in[0];
  const void* emb    = d_in[1];
  const void* Wi0    = d_in[2];
  const void* Wh0    = d_in[3];
  const void* b0     = d_in[4];
  const void* Wi1    = d_in[5];
  const void* Wh1    = d_in[6];
  const void* b1     = d_in[7];
  const void* W_if   = d_in[8];
  const void* b_if   = d_in[9];
  const void* W_out  = d_in[10];
  const void* b_out  = d_in[11];
  const void* W_fc   = d_in[12];
  const void* b_fc   = d_in[13];

  static const int expect[14] = {64*512, 256*512, 2048*576, 2048*512, 2048,
                                 2048*512, 2048*512, 2048, 135*512, 135,
                                 512*576, 512, 256*512, 256};
  bool ok = (n_in == 14);
  if(ok) for(int i=0;i<14;i++) if(in_sizes[i]!=expect[i]) ok=false;

  int*      flags = (int*)d_ws;                   // [0]=dtype flag
  float*    embW  = (float*)d_ws + 64;            // 2048*256
  ushort_t* PA    = (ushort_t*)(embW + 524288);   // region 1310720 f16 (uses 1179648)
  ushort_t* PB    = PA + 1310720;                 // 2097152 f16
  float*    W_ifT = (float*)(PB + 2097152);       // 69632 (pad col 135 = flags)
  float*    b_ifF = W_ifT + 69632;                // 160
  float*    Wc    = b_ifF + 160;                  // 147456
  float*    bc    = Wc + 147456;                  // 256
  u64*      GX0   = (u64*)(bc + 256);             // 16384 u64 = [4 grp][2 ph][2048]
  u64*      GX1   = GX0 + 16384;                  // 16384 u64
  u64*      GXL   = GX1 + 16384;                  // 2048 u64  = [4 grp][2 ph][256]
  bf16*     cat   = (bf16*)(GXL + 2048);          // 64*512*576
  unsigned* FL    = (unsigned*)W_ifT;             // flags in pad column

  size_t need = 9783168ull + 278528ull + 37748736ull;   // = 47,810,432 B
  if(!ok || ws_size < need){
    hipMemsetAsync(d_out, 0, (size_t)out_size*4, stream);
    return;
  }

  k_detect<<<dim3(1), dim3(256), 0, stream>>>(emb, flags);
  k_embW<<<dim3(2048), dim3(256), 0, stream>>>(emb, Wi0, b0, flags, embW);
  k_wpkA<<<dim3(4608), dim3(256), 0, stream>>>(Wh0, Wi0, flags, PA);
  k_wpkB<<<dim3(8192), dim3(256), 0, stream>>>(Wi1, Wh1, flags, PB);
  k_wifT<<<dim3((135*512+255)/256), dim3(256), 0, stream>>>(W_if, b_if, flags, W_ifT, b_ifF);
  k_wc  <<<dim3(576),  dim3(256), 0, stream>>>(W_fc, W_out, b_out, b_fc, flags, Wc, bc);

  void* kargs[] = {
    (void*)&tokens, (void*)&b1, (void*)&flags,
    (void*)&embW, (void*)&PA, (void*)&PB,
    (void*)&W_ifT, (void*)&b_ifF,
    (void*)&GX0, (void*)&GX1, (void*)&GXL, (void*)&FL,
    (void*)&cat
  };
  hipLaunchCooperativeKernel((const void*)k_dnc3, dim3(64), dim3(512), kargs, 0, stream);

  k_out<<<dim3(8,4,64), dim3(256), 0, stream>>>(cat, Wc, bc, (float*)d_out);
}